// Round 11
// baseline (781.057 us; speedup 1.0000x reference)
//
#include <hip/hip_runtime.h>
#include <stdint.h>

#define BATCH 8
#define NPTS  16384
#define BN    (BATCH * NPTS)
#define CH    512                 // points per LDS chunk
#define NCH   (NPTS / CH)         // 32
#define QPB   128                 // 4 waves x 32 queries
#define MARGIN 1.0e-2f            // >> 2*delta(double-bf16-split approx error)

typedef float f32x16 __attribute__((ext_vector_type(16)));
typedef short s16x8  __attribute__((ext_vector_type(8)));

// RNE f32->bf16 bits and back; split2: v = a + b + eps, |eps| <= 2^-18 |v|
__device__ __forceinline__ uint16_t bfr(float x) {
    uint32_t u = __float_as_uint(x);
    return (uint16_t)((u + 0x7FFFu + ((u >> 16) & 1u)) >> 16);
}
__device__ __forceinline__ float bff(uint16_t s) {
    return __uint_as_float(((uint32_t)s) << 16);
}
__device__ __forceinline__ void split2(float v, uint16_t* a, uint16_t* b) {
    *a = bfr(v); *b = bfr(v - bff(*a));
}
__device__ __forceinline__ uint32_t pk2(uint16_t lo, uint16_t hi) {
    return (uint32_t)lo | ((uint32_t)hi << 16);
}

// ---- enc: per point, 16 bf16 B-slots = [1,1,Ya,Yb, H0,M0,H0,M0 | H1,M1,H1,M1, H2,M2,H2,M2]
// (Ya,Yb)=split2(ys), (Hd,Md)=split2(-2*yd). Layout [b][chunk][half][p] of uint4.
__global__ __launch_bounds__(256) void enc_kernel(
    const float* __restrict__ Y, uint4* __restrict__ enc)
{
#pragma clang fp contract(off)
    const int g = blockIdx.x * 256 + threadIdx.x;     // 0..BN-1
    const int b = g >> 14, p = g & (NPTS - 1);
    const float y0 = Y[(size_t)g * 3 + 0];
    const float y1 = Y[(size_t)g * 3 + 1];
    const float y2 = Y[(size_t)g * 3 + 2];
    const float ys = (y0 * y0 + y1 * y1) + y2 * y2;   // np order (approx side)
    uint16_t Ya, Yb; split2(ys, &Ya, &Yb);
    uint16_t H0, M0; split2(-2.0f * y0, &H0, &M0);
    uint16_t H1, M1; split2(-2.0f * y1, &H1, &M1);
    uint16_t H2, M2; split2(-2.0f * y2, &H2, &M2);
    const uint16_t ONE = 0x3F80;
    const int ch = p >> 9, pp = p & (CH - 1);
    const size_t base = (size_t)(b * NCH + ch) * 1024 + pp;
    enc[base]       = make_uint4(pk2(ONE, ONE), pk2(Ya, Yb), pk2(H0, M0), pk2(H0, M0));
    enc[base + 512] = make_uint4(pk2(H1, M1), pk2(H1, M1), pk2(H2, M2), pk2(H2, M2));
}

#define F16(M_) M_(0) M_(1) M_(2) M_(3) M_(4) M_(5) M_(6) M_(7) \
                M_(8) M_(9) M_(10) M_(11) M_(12) M_(13) M_(14) M_(15)

#define MIN3(a, b, c) fminf(fminf((a), (b)), (c))

// Two-sweep exact NN with runtime-calibrated C/D layout (packed to 8 int regs).
__global__ __launch_bounds__(256, 8) void nn_mfma(
    const float* __restrict__ xyz1, const float* __restrict__ xyz2,
    const uint4* __restrict__ encA, const uint4* __restrict__ encB,
    float* __restrict__ out, int ndir, int dir0)
{
#pragma clang fp contract(off)
    __shared__ uint4 lds[2 * CH];                      // 16 KB
    __shared__ unsigned long long keys[QPB];

    const int tid = threadIdx.x;
    const int l   = tid & 63;
    const int wv  = tid >> 6;
    const int col = l & 31;
    const int hi  = l >> 5;

    int dir, batch, xblk;
    {
        const int g = blockIdx.x;
        if (ndir == 2) {                // bijective (dir,batch,xblk) decode
            const int s = 2 * (g & 7) + ((g >> 3) & 1);
            dir = s >> 3; batch = s & 7; xblk = g >> 4;
        } else {
            dir = dir0; batch = g & 7; xblk = g >> 3;
        }
    }

    const float* Xp = dir ? xyz2 : xyz1;
    const float* Yp = dir ? xyz1 : xyz2;
    const uint4* ep = (dir ? encB : encA) + (size_t)batch * (NCH * 1024);
    const int bofs  = batch * NPTS;
    const int qbase = xblk * QPB + wv * 32;            // batch-local

    if (tid < QPB) keys[tid] = ~0ull;

    const f32x16 zf = {0.f,0.f,0.f,0.f,0.f,0.f,0.f,0.f,
                       0.f,0.f,0.f,0.f,0.f,0.f,0.f,0.f};

    // ---- self-calibration: measure actual C/D (row,col) labels, then pack
    // into 8 int regs (row | col<<8, two 16-bit entries per u32) so the f32x16
    // probe results die immediately (R10: keeping them spilled 51 MB scratch).
    int rcpack[8];
    {
        s16x8 pa = {0,0,0,0,0,0,0,0}, pb = {0,0,0,0,0,0,0,0};
        if (hi == 0) { pa[0] = (short)bfr((float)col); pb[0] = (short)0x3F80; }
        const f32x16 rowp = __builtin_amdgcn_mfma_f32_32x32x16_bf16(pa, pb, zf, 0, 0, 0);
        s16x8 pc = {0,0,0,0,0,0,0,0}, pd = {0,0,0,0,0,0,0,0};
        if (hi == 0) { pc[0] = (short)0x3F80; pd[0] = (short)bfr((float)col); }
        const f32x16 colp = __builtin_amdgcn_mfma_f32_32x32x16_bf16(pc, pd, zf, 0, 0, 0);
#define PACKRC(r) { const int e_ = ((int)rowp[r]) | (((int)colp[r]) << 8); \
                    if (((r) & 1) == 0) rcpack[(r) >> 1] = e_; \
                    else                rcpack[(r) >> 1] |= e_ << 16; }
        F16(PACKRC)
#undef PACKRC
    }

    // ---- A fragment: query qbase+col, k-slots of group hi ----
    s16x8 afr;
    {
        const float* xp = Xp + (size_t)(bofs + qbase + col) * 3;
        const float x0 = xp[0], x1 = xp[1], x2 = xp[2];
        const float xs = (x0 * x0 + x1 * x1) + x2 * x2;
        uint16_t Xa, Xb; split2(xs, &Xa, &Xb);
        uint16_t h0, m0; split2(x0, &h0, &m0);
        uint16_t h1, m1; split2(x1, &h1, &m1);
        uint16_t h2, m2; split2(x2, &h2, &m2);
        const uint16_t ONE = 0x3F80;
        if (hi == 0) {
            afr[0]=(short)Xa; afr[1]=(short)Xb; afr[2]=(short)ONE; afr[3]=(short)ONE;
            afr[4]=(short)h0; afr[5]=(short)h0; afr[6]=(short)m0;  afr[7]=(short)m0;
        } else {
            afr[0]=(short)h1; afr[1]=(short)h1; afr[2]=(short)m1;  afr[3]=(short)m1;
            afr[4]=(short)h2; afr[5]=(short)h2; afr[6]=(short)m2;  afr[7]=(short)m2;
        }
    }

    const int ldsb = hi * CH + col;                    // uint4 index

    // ================= sweep 1: per-query approx min =================
    f32x16 run;
#define RINIT(i) run[i] = __builtin_inff();
    F16(RINIT)
#undef RINIT
    for (int c = 0; c < NCH; ++c) {
        __syncthreads();
        {
            const uint4* src = ep + (size_t)c * 1024;
#pragma unroll
            for (int i = 0; i < 4; ++i) lds[i * 256 + tid] = src[i * 256 + tid];
        }
        __syncthreads();
#pragma unroll
        for (int t = 0; t < CH / 32; ++t) {
            const s16x8 bf = *(const s16x8*)&lds[ldsb + t * 32];
            const f32x16 acc = __builtin_amdgcn_mfma_f32_32x32x16_bf16(afr, bf, zf, 0, 0, 0);
#define RMIN(i) run[i] = fminf(run[i], acc[i]);
            F16(RMIN)
#undef RMIN
        }
    }
    // cross-lane min over the 32 cols (masks 1..16 stay within the hi-half)
#pragma unroll
    for (int mk = 1; mk <= 16; mk <<= 1) {
#define XMIN(i) run[i] = fminf(run[i], __shfl_xor(run[i], mk, 64));
        F16(XMIN)
#undef XMIN
    }
    f32x16 cneg;                  // C = -(m'+MARGIN): candidate <=> acc <= 0
#define CNEG(i) cneg[i] = -(run[i] + MARGIN);
    F16(CNEG)
#undef CNEG

    // ====== sweep 2: candidates + exact first-occurrence argmin ======
    for (int c = 0; c < NCH; ++c) {
        __syncthreads();
        {
            const uint4* src = ep + (size_t)c * 1024;
#pragma unroll
            for (int i = 0; i < 4; ++i) lds[i * 256 + tid] = src[i * 256 + tid];
        }
        __syncthreads();
#pragma unroll
        for (int t = 0; t < CH / 32; ++t) {
            const s16x8 bf = *(const s16x8*)&lds[ldsb + t * 32];
            const f32x16 acc = __builtin_amdgcn_mfma_f32_32x32x16_bf16(afr, bf, cneg, 0, 0, 0);
            // v_min3 tree: 16 -> 1 in 8 ops
            const float u0 = MIN3(acc[0],  acc[1],  acc[2]);
            const float u1 = MIN3(acc[3],  acc[4],  acc[5]);
            const float u2 = MIN3(acc[6],  acc[7],  acc[8]);
            const float u3 = MIN3(acc[9],  acc[10], acc[11]);
            const float u4 = MIN3(acc[12], acc[13], acc[14]);
            const float v0 = MIN3(u0, u1, acc[15]);
            const float v1 = MIN3(u2, u3, u4);
            if (fminf(v0, v1) <= 0.0f) {               // rare
#define HITR(r) if (acc[r] <= 0.0f) { \
                    const int w_  = rcpack[(r) >> 1]; \
                    const int e_  = (w_ >> (((r) & 1) * 16)) & 0xFFFF; \
                    const int rl  = e_ & 0xFF; \
                    const int jc  = c * CH + t * 32 + (e_ >> 8); \
                    const float* xq = Xp + (size_t)(bofs + qbase + rl) * 3; \
                    const float qx0 = xq[0], qx1 = xq[1], qx2 = xq[2]; \
                    const float qxs = (qx0 * qx0 + qx1 * qx1) + qx2 * qx2; \
                    const float* yq = Yp + (size_t)(bofs + jc) * 3; \
                    const float py0 = yq[0], py1 = yq[1], py2 = yq[2]; \
                    const float pys = (py0 * py0 + py1 * py1) + py2 * py2; \
                    const float dd = (qxs - 2.0f * ((qx0 * py0 + qx1 * py1) + qx2 * py2)) + pys; \
                    uint32_t kb = __float_as_uint(dd); \
                    kb = (kb & 0x80000000u) ? ~kb : (kb | 0x80000000u); \
                    atomicMin(&keys[wv * 32 + rl], \
                              ((unsigned long long)kb << 32) | (uint32_t)jc); }
                F16(HITR)
#undef HITR
            }
        }
    }

    __syncthreads();
    if (tid < QPB) {
        const unsigned long long m = keys[tid];
        const uint32_t k32 = (uint32_t)(m >> 32);
        const uint32_t db  = (k32 & 0x80000000u) ? (k32 ^ 0x80000000u) : ~k32;
        const size_t gq = (size_t)bofs + (size_t)xblk * QPB + tid;
        float* distp = out + (size_t)dir * BN;
        float* idxp  = out + (size_t)(2 + dir) * BN;
        distp[gq] = __uint_as_float(db);
        idxp[gq]  = (float)(uint32_t)(m & 0xFFFFFFFFu);
    }
}

extern "C" void kernel_launch(void* const* d_in, const int* in_sizes, int n_in,
                              void* d_out, int out_size, void* d_ws, size_t ws_size,
                              hipStream_t stream) {
    const float* xyz1 = (const float*)d_in[0];
    const float* xyz2 = (const float*)d_in[1];
    float* out = (float*)d_out;

    uint4* encA = (uint4*)d_ws;                   // 4 MiB
    uint4* encB = encA + (size_t)BN * 2;          // 4 MiB

    if (ws_size >= (size_t)8 * 1024 * 1024) {
        enc_kernel<<<BN / 256, 256, 0, stream>>>(xyz2, encA);
        enc_kernel<<<BN / 256, 256, 0, stream>>>(xyz1, encB);
        nn_mfma<<<2048, 256, 0, stream>>>(xyz1, xyz2, encA, encB, out, 2, 0);
    } else {                                      // sequential, reuse encA
        enc_kernel<<<BN / 256, 256, 0, stream>>>(xyz2, encA);
        nn_mfma<<<1024, 256, 0, stream>>>(xyz1, xyz2, encA, encA, out, 1, 0);
        enc_kernel<<<BN / 256, 256, 0, stream>>>(xyz1, encA);
        nn_mfma<<<1024, 256, 0, stream>>>(xyz1, xyz2, encA, encA, out, 1, 1);
    }
}

// Round 12
// 577.197 us; speedup vs baseline: 1.3532x; 1.3532x over previous
//
#include <hip/hip_runtime.h>
#include <stdint.h>

#define BATCH 8
#define NPTS  16384
#define BN    (BATCH * NPTS)
#define CH    512                 // points per LDS chunk
#define NCH   (NPTS / CH)         // 32
#define QPB   128                 // 4 waves x 32 queries
#define MARGIN 1.0e-2f            // >> 2*delta(double-bf16-split approx error)

typedef float f32x16 __attribute__((ext_vector_type(16)));
typedef short s16x8  __attribute__((ext_vector_type(8)));

// RNE f32->bf16 bits and back; split2: v = a + b + eps, |eps| <= 2^-18 |v|
__device__ __forceinline__ uint16_t bfr(float x) {
    uint32_t u = __float_as_uint(x);
    return (uint16_t)((u + 0x7FFFu + ((u >> 16) & 1u)) >> 16);
}
__device__ __forceinline__ float bff(uint16_t s) {
    return __uint_as_float(((uint32_t)s) << 16);
}
__device__ __forceinline__ void split2(float v, uint16_t* a, uint16_t* b) {
    *a = bfr(v); *b = bfr(v - bff(*a));
}
__device__ __forceinline__ uint32_t pk2(uint16_t lo, uint16_t hi) {
    return (uint32_t)lo | ((uint32_t)hi << 16);
}

// ---- enc: per point, 16 bf16 B-slots = [1,1,Ya,Yb, H0,M0,H0,M0 | H1,M1,H1,M1, H2,M2,H2,M2]
// (Ya,Yb)=split2(ys), (Hd,Md)=split2(-2*yd). Layout [b][chunk][half][p] of uint4.
__global__ __launch_bounds__(256) void enc_kernel(
    const float* __restrict__ Y, uint4* __restrict__ enc)
{
#pragma clang fp contract(off)
    const int g = blockIdx.x * 256 + threadIdx.x;     // 0..BN-1
    const int b = g >> 14, p = g & (NPTS - 1);
    const float y0 = Y[(size_t)g * 3 + 0];
    const float y1 = Y[(size_t)g * 3 + 1];
    const float y2 = Y[(size_t)g * 3 + 2];
    const float ys = (y0 * y0 + y1 * y1) + y2 * y2;   // np order (approx side)
    uint16_t Ya, Yb; split2(ys, &Ya, &Yb);
    uint16_t H0, M0; split2(-2.0f * y0, &H0, &M0);
    uint16_t H1, M1; split2(-2.0f * y1, &H1, &M1);
    uint16_t H2, M2; split2(-2.0f * y2, &H2, &M2);
    const uint16_t ONE = 0x3F80;
    const int ch = p >> 9, pp = p & (CH - 1);
    const size_t base = (size_t)(b * NCH + ch) * 1024 + pp;
    enc[base]       = make_uint4(pk2(ONE, ONE), pk2(Ya, Yb), pk2(H0, M0), pk2(H0, M0));
    enc[base + 512] = make_uint4(pk2(H1, M1), pk2(H1, M1), pk2(H2, M2), pk2(H2, M2));
}

#define F16(M_) M_(0) M_(1) M_(2) M_(3) M_(4) M_(5) M_(6) M_(7) \
                M_(8) M_(9) M_(10) M_(11) M_(12) M_(13) M_(14) M_(15)

#define MIN3(a, b, c) fminf(fminf((a), (b)), (c))

// Two-sweep exact NN with runtime-calibrated C/D layout (packed to 8 int regs).
// __launch_bounds__(256,4): 128-VGPR cap. (256,8) capped at 64 and spilled the
// hot-loop state -> 2.7 GB scratch traffic (R11). Occupancy is NOT the limiter.
__global__ __launch_bounds__(256, 4) void nn_mfma(
    const float* __restrict__ xyz1, const float* __restrict__ xyz2,
    const uint4* __restrict__ encA, const uint4* __restrict__ encB,
    float* __restrict__ out, int ndir, int dir0)
{
#pragma clang fp contract(off)
    __shared__ uint4 lds[2 * CH];                      // 16 KB
    __shared__ unsigned long long keys[QPB];

    const int tid = threadIdx.x;
    const int l   = tid & 63;
    const int wv  = tid >> 6;
    const int col = l & 31;
    const int hi  = l >> 5;

    int dir, batch, xblk;
    {
        const int g = blockIdx.x;
        if (ndir == 2) {                // bijective (dir,batch,xblk) decode
            const int s = 2 * (g & 7) + ((g >> 3) & 1);
            dir = s >> 3; batch = s & 7; xblk = g >> 4;
        } else {
            dir = dir0; batch = g & 7; xblk = g >> 3;
        }
    }

    const float* Xp = dir ? xyz2 : xyz1;
    const float* Yp = dir ? xyz1 : xyz2;
    const uint4* ep = (dir ? encB : encA) + (size_t)batch * (NCH * 1024);
    const int bofs  = batch * NPTS;
    const int qbase = xblk * QPB + wv * 32;            // batch-local

    if (tid < QPB) keys[tid] = ~0ull;

    const f32x16 zf = {0.f,0.f,0.f,0.f,0.f,0.f,0.f,0.f,
                       0.f,0.f,0.f,0.f,0.f,0.f,0.f,0.f};

    // ---- self-calibration: measure actual C/D (row,col) labels, then pack
    // into 8 int regs (row | col<<8, two 16-bit entries per u32).
    int rcpack[8];
    {
        s16x8 pa = {0,0,0,0,0,0,0,0}, pb = {0,0,0,0,0,0,0,0};
        if (hi == 0) { pa[0] = (short)bfr((float)col); pb[0] = (short)0x3F80; }
        const f32x16 rowp = __builtin_amdgcn_mfma_f32_32x32x16_bf16(pa, pb, zf, 0, 0, 0);
        s16x8 pc = {0,0,0,0,0,0,0,0}, pd = {0,0,0,0,0,0,0,0};
        if (hi == 0) { pc[0] = (short)0x3F80; pd[0] = (short)bfr((float)col); }
        const f32x16 colp = __builtin_amdgcn_mfma_f32_32x32x16_bf16(pc, pd, zf, 0, 0, 0);
#define PACKRC(r) { const int e_ = ((int)rowp[r]) | (((int)colp[r]) << 8); \
                    if (((r) & 1) == 0) rcpack[(r) >> 1] = e_; \
                    else                rcpack[(r) >> 1] |= e_ << 16; }
        F16(PACKRC)
#undef PACKRC
    }

    // ---- A fragment: query qbase+col, k-slots of group hi ----
    s16x8 afr;
    {
        const float* xp = Xp + (size_t)(bofs + qbase + col) * 3;
        const float x0 = xp[0], x1 = xp[1], x2 = xp[2];
        const float xs = (x0 * x0 + x1 * x1) + x2 * x2;
        uint16_t Xa, Xb; split2(xs, &Xa, &Xb);
        uint16_t h0, m0; split2(x0, &h0, &m0);
        uint16_t h1, m1; split2(x1, &h1, &m1);
        uint16_t h2, m2; split2(x2, &h2, &m2);
        const uint16_t ONE = 0x3F80;
        if (hi == 0) {
            afr[0]=(short)Xa; afr[1]=(short)Xb; afr[2]=(short)ONE; afr[3]=(short)ONE;
            afr[4]=(short)h0; afr[5]=(short)h0; afr[6]=(short)m0;  afr[7]=(short)m0;
        } else {
            afr[0]=(short)h1; afr[1]=(short)h1; afr[2]=(short)m1;  afr[3]=(short)m1;
            afr[4]=(short)h2; afr[5]=(short)h2; afr[6]=(short)m2;  afr[7]=(short)m2;
        }
    }

    const int ldsb = hi * CH + col;                    // uint4 index

    // ================= sweep 1: per-query approx min =================
    f32x16 run;
#define RINIT(i) run[i] = __builtin_inff();
    F16(RINIT)
#undef RINIT
    for (int c = 0; c < NCH; ++c) {
        __syncthreads();
        {
            const uint4* src = ep + (size_t)c * 1024;
#pragma unroll
            for (int i = 0; i < 4; ++i) lds[i * 256 + tid] = src[i * 256 + tid];
        }
        __syncthreads();
#pragma unroll
        for (int t = 0; t < CH / 32; ++t) {
            const s16x8 bf = *(const s16x8*)&lds[ldsb + t * 32];
            const f32x16 acc = __builtin_amdgcn_mfma_f32_32x32x16_bf16(afr, bf, zf, 0, 0, 0);
#define RMIN(i) run[i] = fminf(run[i], acc[i]);
            F16(RMIN)
#undef RMIN
        }
    }
    // cross-lane min over the 32 cols (masks 1..16 stay within the hi-half)
#pragma unroll
    for (int mk = 1; mk <= 16; mk <<= 1) {
#define XMIN(i) run[i] = fminf(run[i], __shfl_xor(run[i], mk, 64));
        F16(XMIN)
#undef XMIN
    }
    f32x16 cneg;                  // C = -(m'+MARGIN): candidate <=> acc <= 0
#define CNEG(i) cneg[i] = -(run[i] + MARGIN);
    F16(CNEG)
#undef CNEG

    // ====== sweep 2: candidates + exact first-occurrence argmin ======
    for (int c = 0; c < NCH; ++c) {
        __syncthreads();
        {
            const uint4* src = ep + (size_t)c * 1024;
#pragma unroll
            for (int i = 0; i < 4; ++i) lds[i * 256 + tid] = src[i * 256 + tid];
        }
        __syncthreads();
#pragma unroll
        for (int t = 0; t < CH / 32; ++t) {
            const s16x8 bf = *(const s16x8*)&lds[ldsb + t * 32];
            const f32x16 acc = __builtin_amdgcn_mfma_f32_32x32x16_bf16(afr, bf, cneg, 0, 0, 0);
            // v_min3 tree: 16 -> 1 in 8 ops
            const float u0 = MIN3(acc[0],  acc[1],  acc[2]);
            const float u1 = MIN3(acc[3],  acc[4],  acc[5]);
            const float u2 = MIN3(acc[6],  acc[7],  acc[8]);
            const float u3 = MIN3(acc[9],  acc[10], acc[11]);
            const float u4 = MIN3(acc[12], acc[13], acc[14]);
            const float v0 = MIN3(u0, u1, acc[15]);
            const float v1 = MIN3(u2, u3, u4);
            if (fminf(v0, v1) <= 0.0f) {               // rare
#define HITR(r) if (acc[r] <= 0.0f) { \
                    const int w_  = rcpack[(r) >> 1]; \
                    const int e_  = (w_ >> (((r) & 1) * 16)) & 0xFFFF; \
                    const int rl  = e_ & 0xFF; \
                    const int jc  = c * CH + t * 32 + (e_ >> 8); \
                    const float* xq = Xp + (size_t)(bofs + qbase + rl) * 3; \
                    const float qx0 = xq[0], qx1 = xq[1], qx2 = xq[2]; \
                    const float qxs = (qx0 * qx0 + qx1 * qx1) + qx2 * qx2; \
                    const float* yq = Yp + (size_t)(bofs + jc) * 3; \
                    const float py0 = yq[0], py1 = yq[1], py2 = yq[2]; \
                    const float pys = (py0 * py0 + py1 * py1) + py2 * py2; \
                    const float dd = (qxs - 2.0f * ((qx0 * py0 + qx1 * py1) + qx2 * py2)) + pys; \
                    uint32_t kb = __float_as_uint(dd); \
                    kb = (kb & 0x80000000u) ? ~kb : (kb | 0x80000000u); \
                    atomicMin(&keys[wv * 32 + rl], \
                              ((unsigned long long)kb << 32) | (uint32_t)jc); }
                F16(HITR)
#undef HITR
            }
        }
    }

    __syncthreads();
    if (tid < QPB) {
        const unsigned long long m = keys[tid];
        const uint32_t k32 = (uint32_t)(m >> 32);
        const uint32_t db  = (k32 & 0x80000000u) ? (k32 ^ 0x80000000u) : ~k32;
        const size_t gq = (size_t)bofs + (size_t)xblk * QPB + tid;
        float* distp = out + (size_t)dir * BN;
        float* idxp  = out + (size_t)(2 + dir) * BN;
        distp[gq] = __uint_as_float(db);
        idxp[gq]  = (float)(uint32_t)(m & 0xFFFFFFFFu);
    }
}

extern "C" void kernel_launch(void* const* d_in, const int* in_sizes, int n_in,
                              void* d_out, int out_size, void* d_ws, size_t ws_size,
                              hipStream_t stream) {
    const float* xyz1 = (const float*)d_in[0];
    const float* xyz2 = (const float*)d_in[1];
    float* out = (float*)d_out;

    uint4* encA = (uint4*)d_ws;                   // 4 MiB
    uint4* encB = encA + (size_t)BN * 2;          // 4 MiB

    if (ws_size >= (size_t)8 * 1024 * 1024) {
        enc_kernel<<<BN / 256, 256, 0, stream>>>(xyz2, encA);
        enc_kernel<<<BN / 256, 256, 0, stream>>>(xyz1, encB);
        nn_mfma<<<2048, 256, 0, stream>>>(xyz1, xyz2, encA, encB, out, 2, 0);
    } else {                                      // sequential, reuse encA
        enc_kernel<<<BN / 256, 256, 0, stream>>>(xyz2, encA);
        nn_mfma<<<1024, 256, 0, stream>>>(xyz1, xyz2, encA, encA, out, 1, 0);
        enc_kernel<<<BN / 256, 256, 0, stream>>>(xyz1, encA);
        nn_mfma<<<1024, 256, 0, stream>>>(xyz1, xyz2, encA, encA, out, 1, 1);
    }
}

// Round 13
// 497.498 us; speedup vs baseline: 1.5700x; 1.1602x over previous
//
#include <hip/hip_runtime.h>
#include <stdint.h>

#define BATCH 8
#define NPTS  16384
#define BN    (BATCH * NPTS)
#define CH    512                 // points per LDS chunk
#define NCH   (NPTS / CH)         // 32
#define QPB   128                 // 4 waves x 32 queries
#define MARGIN 1.0e-2f            // >> 2*delta(double-bf16-split approx error)

typedef float f32x16 __attribute__((ext_vector_type(16)));
typedef short s16x8  __attribute__((ext_vector_type(8)));

// RNE f32->bf16 bits and back; split2: v = a + b + eps, |eps| <= 2^-18 |v|
__device__ __forceinline__ uint16_t bfr(float x) {
    uint32_t u = __float_as_uint(x);
    return (uint16_t)((u + 0x7FFFu + ((u >> 16) & 1u)) >> 16);
}
__device__ __forceinline__ float bff(uint16_t s) {
    return __uint_as_float(((uint32_t)s) << 16);
}
__device__ __forceinline__ void split2(float v, uint16_t* a, uint16_t* b) {
    *a = bfr(v); *b = bfr(v - bff(*a));
}
__device__ __forceinline__ uint32_t pk2(uint16_t lo, uint16_t hi) {
    return (uint32_t)lo | ((uint32_t)hi << 16);
}

// ---- enc: per point, 16 bf16 B-slots = [1,1,Ya,Yb, H0,M0,H0,M0 | H1,M1,H1,M1, H2,M2,H2,M2]
// (Ya,Yb)=split2(ys), (Hd,Md)=split2(-2*yd). Layout [b][chunk][half][p] of uint4.
__global__ __launch_bounds__(256) void enc_kernel(
    const float* __restrict__ Y, uint4* __restrict__ enc)
{
#pragma clang fp contract(off)
    const int g = blockIdx.x * 256 + threadIdx.x;     // 0..BN-1
    const int b = g >> 14, p = g & (NPTS - 1);
    const float y0 = Y[(size_t)g * 3 + 0];
    const float y1 = Y[(size_t)g * 3 + 1];
    const float y2 = Y[(size_t)g * 3 + 2];
    const float ys = (y0 * y0 + y1 * y1) + y2 * y2;   // np order (approx side)
    uint16_t Ya, Yb; split2(ys, &Ya, &Yb);
    uint16_t H0, M0; split2(-2.0f * y0, &H0, &M0);
    uint16_t H1, M1; split2(-2.0f * y1, &H1, &M1);
    uint16_t H2, M2; split2(-2.0f * y2, &H2, &M2);
    const uint16_t ONE = 0x3F80;
    const int ch = p >> 9, pp = p & (CH - 1);
    const size_t base = (size_t)(b * NCH + ch) * 1024 + pp;
    enc[base]       = make_uint4(pk2(ONE, ONE), pk2(Ya, Yb), pk2(H0, M0), pk2(H0, M0));
    enc[base + 512] = make_uint4(pk2(H1, M1), pk2(H1, M1), pk2(H2, M2), pk2(H2, M2));
}

#define F16(M_) M_(0) M_(1) M_(2) M_(3) M_(4) M_(5) M_(6) M_(7) \
                M_(8) M_(9) M_(10) M_(11) M_(12) M_(13) M_(14) M_(15)

#define MIN3(a, b, c) fminf(fminf((a), (b)), (c))

// Two-sweep exact NN, runtime-calibrated C/D layout, double-buffered LDS with
// global_load_lds prefetch (1 barrier/phase), min3 two-tile folding.
__global__ __launch_bounds__(256, 4) void nn_mfma(
    const float* __restrict__ xyz1, const float* __restrict__ xyz2,
    const uint4* __restrict__ encA, const uint4* __restrict__ encB,
    float* __restrict__ out, int ndir, int dir0)
{
#pragma clang fp contract(off)
    __shared__ uint4 lds[2][2 * CH];                   // 2 x 16 KB
    __shared__ unsigned long long keys[QPB];

    const int tid = threadIdx.x;
    const int l   = tid & 63;
    const int wv  = tid >> 6;
    const int col = l & 31;
    const int hi  = l >> 5;

    int dir, batch, xblk;
    {
        const int g = blockIdx.x;
        if (ndir == 2) {                // bijective (dir,batch,xblk) decode
            const int s = 2 * (g & 7) + ((g >> 3) & 1);
            dir = s >> 3; batch = s & 7; xblk = g >> 4;
        } else {
            dir = dir0; batch = g & 7; xblk = g >> 3;
        }
    }

    const float* Xp = dir ? xyz2 : xyz1;
    const float* Yp = dir ? xyz1 : xyz2;
    const uint4* ep = (dir ? encB : encA) + (size_t)batch * (NCH * 1024);
    const int bofs  = batch * NPTS;
    const int qbase = xblk * QPB + wv * 32;            // batch-local

    if (tid < QPB) keys[tid] = ~0ull;

    const f32x16 zf = {0.f,0.f,0.f,0.f,0.f,0.f,0.f,0.f,
                       0.f,0.f,0.f,0.f,0.f,0.f,0.f,0.f};

    // ---- self-calibration: actual C/D (row,col) labels, packed to 8 ints ----
    int rcpack[8];
    {
        s16x8 pa = {0,0,0,0,0,0,0,0}, pb = {0,0,0,0,0,0,0,0};
        if (hi == 0) { pa[0] = (short)bfr((float)col); pb[0] = (short)0x3F80; }
        const f32x16 rowp = __builtin_amdgcn_mfma_f32_32x32x16_bf16(pa, pb, zf, 0, 0, 0);
        s16x8 pc = {0,0,0,0,0,0,0,0}, pd = {0,0,0,0,0,0,0,0};
        if (hi == 0) { pc[0] = (short)0x3F80; pd[0] = (short)bfr((float)col); }
        const f32x16 colp = __builtin_amdgcn_mfma_f32_32x32x16_bf16(pc, pd, zf, 0, 0, 0);
#define PACKRC(r) { const int e_ = ((int)rowp[r]) | (((int)colp[r]) << 8); \
                    if (((r) & 1) == 0) rcpack[(r) >> 1] = e_; \
                    else                rcpack[(r) >> 1] |= e_ << 16; }
        F16(PACKRC)
#undef PACKRC
    }

    // ---- A fragment: query qbase+col, k-slots of group hi ----
    s16x8 afr;
    {
        const float* xp = Xp + (size_t)(bofs + qbase + col) * 3;
        const float x0 = xp[0], x1 = xp[1], x2 = xp[2];
        const float xs = (x0 * x0 + x1 * x1) + x2 * x2;
        uint16_t Xa, Xb; split2(xs, &Xa, &Xb);
        uint16_t h0, m0; split2(x0, &h0, &m0);
        uint16_t h1, m1; split2(x1, &h1, &m1);
        uint16_t h2, m2; split2(x2, &h2, &m2);
        const uint16_t ONE = 0x3F80;
        if (hi == 0) {
            afr[0]=(short)Xa; afr[1]=(short)Xb; afr[2]=(short)ONE; afr[3]=(short)ONE;
            afr[4]=(short)h0; afr[5]=(short)h0; afr[6]=(short)m0;  afr[7]=(short)m0;
        } else {
            afr[0]=(short)h1; afr[1]=(short)h1; afr[2]=(short)m1;  afr[3]=(short)m1;
            afr[4]=(short)h2; afr[5]=(short)h2; afr[6]=(short)m2;  afr[7]=(short)m2;
        }
    }

    const int ldsb = hi * CH + col;                    // uint4 index
    const int wb   = tid & 192;                        // wave base within block

    // async stage chunk c into LDS buffer buf (linear dest: base + lane*16)
#define STAGE(c, buf) { \
        const uint4* src_ = ep + (size_t)(c) * 1024; \
        _Pragma("unroll") \
        for (int i_ = 0; i_ < 4; ++i_) \
            __builtin_amdgcn_global_load_lds( \
                (const __attribute__((address_space(1))) void*)(src_ + i_ * 256 + tid), \
                (__attribute__((address_space(3))) void*)&lds[buf][i_ * 256 + wb + l], \
                16, 0, 0); \
    }

    // ================= sweep 1: per-query approx min =================
    f32x16 run;
#define RINIT(i) run[i] = __builtin_inff();
    F16(RINIT)
#undef RINIT
    STAGE(0, 0);
    __syncthreads();
    int cur = 0;
    for (int c = 0; c < NCH; ++c) {
        if (c + 1 < NCH) STAGE(c + 1, cur ^ 1);        // prefetch under compute
#pragma unroll
        for (int tp = 0; tp < CH / 64; ++tp) {
            const s16x8 bfA = *(const s16x8*)&lds[cur][ldsb + (2 * tp) * 32];
            const s16x8 bfB = *(const s16x8*)&lds[cur][ldsb + (2 * tp + 1) * 32];
            const f32x16 accA = __builtin_amdgcn_mfma_f32_32x32x16_bf16(afr, bfA, zf, 0, 0, 0);
            const f32x16 accB = __builtin_amdgcn_mfma_f32_32x32x16_bf16(afr, bfB, zf, 0, 0, 0);
#define RMIN3(i) run[i] = MIN3(run[i], accA[i], accB[i]);
            F16(RMIN3)
#undef RMIN3
        }
        __syncthreads();                                // drains prefetch too
        cur ^= 1;
    }
    // cross-lane min over the 32 cols (masks 1..16 stay within the hi-half)
#pragma unroll
    for (int mk = 1; mk <= 16; mk <<= 1) {
#define XMIN(i) run[i] = fminf(run[i], __shfl_xor(run[i], mk, 64));
        F16(XMIN)
#undef XMIN
    }
    f32x16 cneg;                  // C = -(m'+MARGIN): candidate <=> acc <= 0
#define CNEG(i) cneg[i] = -(run[i] + MARGIN);
    F16(CNEG)
#undef CNEG

    // ====== sweep 2: candidates + exact first-occurrence argmin ======
#define HITR(accv, jb, r) if ((accv)[r] <= 0.0f) { \
        const int w_  = rcpack[(r) >> 1]; \
        const int e_  = (w_ >> (((r) & 1) * 16)) & 0xFFFF; \
        const int rl  = e_ & 0xFF; \
        const int jc  = (jb) + (e_ >> 8); \
        const float* xq = Xp + (size_t)(bofs + qbase + rl) * 3; \
        const float qx0 = xq[0], qx1 = xq[1], qx2 = xq[2]; \
        const float qxs = (qx0 * qx0 + qx1 * qx1) + qx2 * qx2; \
        const float* yq = Yp + (size_t)(bofs + jc) * 3; \
        const float py0 = yq[0], py1 = yq[1], py2 = yq[2]; \
        const float pys = (py0 * py0 + py1 * py1) + py2 * py2; \
        const float dd = (qxs - 2.0f * ((qx0 * py0 + qx1 * py1) + qx2 * py2)) + pys; \
        uint32_t kb = __float_as_uint(dd); \
        kb = (kb & 0x80000000u) ? ~kb : (kb | 0x80000000u); \
        atomicMin(&keys[wv * 32 + rl], \
                  ((unsigned long long)kb << 32) | (uint32_t)jc); }
#define HIT16(accv, jb) { \
        const float u0 = MIN3((accv)[0],  (accv)[1],  (accv)[2]); \
        const float u1 = MIN3((accv)[3],  (accv)[4],  (accv)[5]); \
        const float u2 = MIN3((accv)[6],  (accv)[7],  (accv)[8]); \
        const float u3 = MIN3((accv)[9],  (accv)[10], (accv)[11]); \
        const float u4 = MIN3((accv)[12], (accv)[13], (accv)[14]); \
        const float v0 = MIN3(u0, u1, (accv)[15]); \
        const float v1 = MIN3(u2, u3, u4); \
        if (fminf(v0, v1) <= 0.0f) { \
            F16_HIT(accv, jb) \
        } }
#define F16_HIT(accv, jb) \
        HITR(accv, jb, 0) HITR(accv, jb, 1) HITR(accv, jb, 2) HITR(accv, jb, 3) \
        HITR(accv, jb, 4) HITR(accv, jb, 5) HITR(accv, jb, 6) HITR(accv, jb, 7) \
        HITR(accv, jb, 8) HITR(accv, jb, 9) HITR(accv, jb, 10) HITR(accv, jb, 11) \
        HITR(accv, jb, 12) HITR(accv, jb, 13) HITR(accv, jb, 14) HITR(accv, jb, 15)

    STAGE(0, cur);
    __syncthreads();
    for (int c = 0; c < NCH; ++c) {
        if (c + 1 < NCH) STAGE(c + 1, cur ^ 1);        // prefetch under compute
#pragma unroll
        for (int tp = 0; tp < CH / 64; ++tp) {
            const s16x8 bfA = *(const s16x8*)&lds[cur][ldsb + (2 * tp) * 32];
            const s16x8 bfB = *(const s16x8*)&lds[cur][ldsb + (2 * tp + 1) * 32];
            const f32x16 accA = __builtin_amdgcn_mfma_f32_32x32x16_bf16(afr, bfA, cneg, 0, 0, 0);
            const f32x16 accB = __builtin_amdgcn_mfma_f32_32x32x16_bf16(afr, bfB, cneg, 0, 0, 0);
            const int jbA = c * CH + (2 * tp) * 32;
            HIT16(accA, jbA)
            HIT16(accB, jbA + 32)
        }
        __syncthreads();
        cur ^= 1;
    }
#undef HIT16
#undef F16_HIT
#undef HITR

    __syncthreads();
    if (tid < QPB) {
        const unsigned long long m = keys[tid];
        const uint32_t k32 = (uint32_t)(m >> 32);
        const uint32_t db  = (k32 & 0x80000000u) ? (k32 ^ 0x80000000u) : ~k32;
        const size_t gq = (size_t)bofs + (size_t)xblk * QPB + tid;
        float* distp = out + (size_t)dir * BN;
        float* idxp  = out + (size_t)(2 + dir) * BN;
        distp[gq] = __uint_as_float(db);
        idxp[gq]  = (float)(uint32_t)(m & 0xFFFFFFFFu);
    }
}

extern "C" void kernel_launch(void* const* d_in, const int* in_sizes, int n_in,
                              void* d_out, int out_size, void* d_ws, size_t ws_size,
                              hipStream_t stream) {
    const float* xyz1 = (const float*)d_in[0];
    const float* xyz2 = (const float*)d_in[1];
    float* out = (float*)d_out;

    uint4* encA = (uint4*)d_ws;                   // 4 MiB
    uint4* encB = encA + (size_t)BN * 2;          // 4 MiB

    if (ws_size >= (size_t)8 * 1024 * 1024) {
        enc_kernel<<<BN / 256, 256, 0, stream>>>(xyz2, encA);
        enc_kernel<<<BN / 256, 256, 0, stream>>>(xyz1, encB);
        nn_mfma<<<2048, 256, 0, stream>>>(xyz1, xyz2, encA, encB, out, 2, 0);
    } else {                                      // sequential, reuse encA
        enc_kernel<<<BN / 256, 256, 0, stream>>>(xyz2, encA);
        nn_mfma<<<1024, 256, 0, stream>>>(xyz1, xyz2, encA, encA, out, 1, 0);
        enc_kernel<<<BN / 256, 256, 0, stream>>>(xyz1, encA);
        nn_mfma<<<1024, 256, 0, stream>>>(xyz1, xyz2, encA, encA, out, 1, 1);
    }
}